// Round 7
// baseline (257.599 us; speedup 1.0000x reference)
//
#include <hip/hip_runtime.h>

// B=2, L=2048, DIM=1024, H=16, HD=64; scale folded into Q: 0.125*log2e; mask: -60*log2e
#define LL 2048
#define NHEADS 16
#define HDIM 64
#define QSCALE 0.18033688011112042f   // 0.125 * log2(e)
#define MASKC1 -86.56170245333780f    // -60 * log2(e)

typedef __attribute__((ext_vector_type(8))) __bf16 bf16x8;
typedef __attribute__((ext_vector_type(4))) float f32x4;
typedef __attribute__((ext_vector_type(16))) float f32x16;
typedef __attribute__((ext_vector_type(4))) int i32x4;

__device__ __forceinline__ unsigned short f2bf(float f) {
  unsigned int u = __builtin_bit_cast(unsigned int, f);
  u += 0x7fffu + ((u >> 16) & 1u);   // RNE
  return (unsigned short)(u >> 16);
}

__device__ __forceinline__ bf16x8 ld_frag(const unsigned short* p) {
  return *reinterpret_cast<const bf16x8*>(p);
}

// async global->LDS, 16B per lane; LDS dest = wave-uniform base + lane*16
__device__ __forceinline__ void async_cp16(const unsigned short* g, unsigned short* l) {
  __builtin_amdgcn_global_load_lds(
      (const __attribute__((address_space(1))) unsigned int*)(unsigned long long)(g),
      (__attribute__((address_space(3))) unsigned int*)(unsigned int)(unsigned long long)(l),
      16, 0, 0);
}

// ---------------- fused prep: x fp32->bf16 (blocks 0..4095) + W transpose (4096..4863) ----------
__global__ __launch_bounds__(256) void prep_kernel(
    const float* __restrict__ x, const float* __restrict__ Wq, const float* __restrict__ Wk,
    const float* __restrict__ Wv, unsigned short* __restrict__ xb,
    unsigned short* __restrict__ WtAll) {
  __shared__ float t[64][65];
  int blk = blockIdx.x;
  if (blk < 4096) {
    int i = (blk * 256 + threadIdx.x) * 4;
    float4 v = *reinterpret_cast<const float4*>(x + i);
    ushort4 o;
    o.x = f2bf(v.x); o.y = f2bf(v.y); o.z = f2bf(v.z); o.w = f2bf(v.w);
    *reinterpret_cast<ushort4*>(xb + i) = o;
  } else {
    int idx = blk - 4096;
    int z = idx >> 8; idx &= 255;
    const float* W = (z == 0) ? Wq : (z == 1) ? Wk : Wv;
    unsigned short* dst = WtAll + (size_t)z * 1024 * 1024;
    int n0 = (idx & 15) * 64, k0 = (idx >> 4) * 64;
    int tx = threadIdx.x & 63, ty = threadIdx.x >> 6;
#pragma unroll
    for (int p = 0; p < 16; ++p) {
      int kr = p * 4 + ty;
      t[kr][tx] = W[(size_t)(k0 + kr) * 1024 + n0 + tx];
    }
    __syncthreads();
#pragma unroll
    for (int p = 0; p < 16; ++p) {
      int nr = p * 4 + ty;
      dst[(size_t)(n0 + nr) * 1024 + k0 + tx] = f2bf(t[tx][nr]);
    }
  }
}

// ---------------- prep: em_t = bf16(exp2(mask*MASKC1)) transposed: [b][kt][kh][c32][q2048] ----
// grid 2048: blk = b*1024 + kt*32 + qt. LDS-staged 64q x 64k transpose.
__global__ __launch_bounds__(256) void em_prep_kernel(const float* __restrict__ mask,
                                                      unsigned short* __restrict__ em) {
  __shared__ float t[64][65];
  int blk = blockIdx.x;
  int qt = blk & 31, kt = (blk >> 5) & 31, b = blk >> 10;
  int q0 = qt * 64;
  int tx = threadIdx.x & 63, ty = threadIdx.x >> 6;
#pragma unroll
  for (int p = 0; p < 16; ++p) {
    int qr = p * 4 + ty;
    t[qr][tx] = mask[((size_t)b * LL + q0 + qr) * LL + kt * 64 + tx];
  }
  __syncthreads();
#pragma unroll
  for (int p = 0; p < 16; ++p) {
    int c64 = p * 4 + ty;                 // key within tile
    int kh = c64 >> 5, c = c64 & 31;
    em[((((size_t)b * 32 + kt) * 2 + kh) * 32 + c) * LL + q0 + tx] =
        f2bf(__builtin_amdgcn_exp2f(t[tx][c64] * MASKC1));
  }
}

// ---------------- QKV projection GEMM (async staging, swizzled rows) ----------------
// grid (8, 32, 3). z==0: Q bf16 [bh][l][d] * QSCALE; z==1: K [bh][l][d];
// z==2: V^T tile-major [bh][tile=l/64][d][key64] (plain, no permutation).
__global__ __launch_bounds__(256) void qkv_gemm_kernel(
    const unsigned short* __restrict__ xb, const unsigned short* __restrict__ WtAll,
    const float* __restrict__ bq, const float* __restrict__ bk, const float* __restrict__ bv,
    unsigned short* __restrict__ qkv) {
  const int z = blockIdx.z;
  const unsigned short* Wt = WtAll + (size_t)z * 1024 * 1024;
  const float* bias = (z == 0) ? bq : (z == 1) ? bk : bv;
  unsigned short* outb = qkv + (size_t)z * 4194304;

  __shared__ __align__(16) unsigned short smem[16384];
  unsigned short* As = smem;
  unsigned short* Bs = smem + 8192;

  const int tid = threadIdx.x;
  const int w = tid >> 6, lane = tid & 63, g = lane >> 4, cc = lane & 15;
  const int wm = w >> 1, wn = w & 1;
  const int m0 = blockIdx.y * 128, n0 = blockIdx.x * 128;
  const int srow = lane >> 3;
  const int gc = ((lane & 7) - srow) & 7;
  const unsigned short* ga = xb + (size_t)(m0 + w * 32 + srow) * 1024 + gc * 8;
  const unsigned short* gb = Wt + (size_t)(n0 + w * 32 + srow) * 1024 + gc * 8;
  unsigned short* la = As + w * 2048;
  unsigned short* lb = Bs + w * 2048;

  f32x4 acc[4][4];
#pragma unroll
  for (int i = 0; i < 4; ++i)
#pragma unroll
    for (int j = 0; j < 4; ++j) acc[i][j] = (f32x4)0.0f;

  for (int kk = 0; kk < 1024; kk += 64) {
    __syncthreads();
#pragma unroll
    for (int i = 0; i < 4; ++i) {
      async_cp16(ga + i * 8192 + kk, la + i * 512);
      async_cp16(gb + i * 8192 + kk, lb + i * 512);
    }
    __syncthreads();
    bf16x8 af[4][2], bfr[4][2];
#pragma unroll
    for (int mt = 0; mt < 4; ++mt)
#pragma unroll
      for (int ks = 0; ks < 2; ++ks)
        af[mt][ks] = ld_frag(&As[(wm * 64 + mt * 16 + cc) * 64 + ((4 * ks + g + cc) & 7) * 8]);
#pragma unroll
    for (int nt = 0; nt < 4; ++nt)
#pragma unroll
      for (int ks = 0; ks < 2; ++ks)
        bfr[nt][ks] = ld_frag(&Bs[(wn * 64 + nt * 16 + cc) * 64 + ((4 * ks + g + cc) & 7) * 8]);
#pragma unroll
    for (int mt = 0; mt < 4; ++mt)
#pragma unroll
      for (int nt = 0; nt < 4; ++nt)
#pragma unroll
        for (int ks = 0; ks < 2; ++ks)
          acc[mt][nt] = __builtin_amdgcn_mfma_f32_16x16x32_bf16(af[mt][ks], bfr[nt][ks],
                                                                acc[mt][nt], 0, 0, 0);
  }

  if (z != 2) {
    const float sc = (z == 0) ? QSCALE : 1.0f;
#pragma unroll
    for (int nt = 0; nt < 4; ++nt) {
      int n = n0 + wn * 64 + nt * 16 + cc;
      float bval = bias[n];
      int h = n >> 6, d = n & 63;
#pragma unroll
      for (int mt = 0; mt < 4; ++mt) {
#pragma unroll
        for (int r = 0; r < 4; ++r) {
          int m = m0 + wm * 64 + mt * 16 + g * 4 + r;
          int b = m >> 11, l = m & 2047;
          outb[(((size_t)(b * NHEADS + h) * LL) + l) * HDIM + d] =
              f2bf((acc[mt][nt][r] + bval) * sc);
        }
      }
    }
  } else {
    // V^T tile-major, plain key order: smem[d 128][key 128] then coalesced writes
    __syncthreads();
#pragma unroll
    for (int nt = 0; nt < 4; ++nt) {
      int nr = wn * 64 + nt * 16 + cc;
      float bval = bias[n0 + nr];
#pragma unroll
      for (int mt = 0; mt < 4; ++mt)
#pragma unroll
        for (int r = 0; r < 4; ++r)
          smem[nr * 128 + wm * 64 + mt * 16 + g * 4 + r] = f2bf(acc[mt][nt][r] + bval);
    }
    __syncthreads();
    int row = tid >> 1, half = tid & 1;
    int n = n0 + row, hh = n >> 6, dd = n & 63;
    int bb = m0 >> 11;
    int tI = ((m0 & 2047) >> 6) + half;
    unsigned short* dst =
        outb + (size_t)(bb * NHEADS + hh) * (LL * HDIM) + (size_t)tI * 4096 + dd * 64;
#pragma unroll
    for (int i = 0; i < 8; ++i)
      *reinterpret_cast<uint4*>(dst + i * 8) =
          *reinterpret_cast<const uint4*>(&smem[row * 128 + half * 64 + i * 8]);
  }
}

// ---------------- flash attention: 32x32 core, 8 waves, key-half split ----------------
// grid (16, 32): 128-row q-tiles, 512 thr = 8 waves. Wave w: q rows [32*(w&3),+32),
// key half kh=w>>2 (keys [32kh,+32) of every kt tile). O/li are plain sums (no max-sub)
// so half-key partials merge additively in the epilogue. LDS 64KB -> 2 blocks/CU
// (16 waves/CU, 4/SIMD). One barrier per kt; K/V ping-pong staged; P wave-private.
__global__ __launch_bounds__(512, 4) void flash_kernel(
    const unsigned short* __restrict__ Qb, const unsigned short* __restrict__ Kb,
    const unsigned short* __restrict__ Vt, const unsigned short* __restrict__ Em,
    float* __restrict__ out) {
  const int bh = blockIdx.y, b = bh >> 4, h = bh & 15;
  const int q0 = blockIdx.x * 128;
  const int tid = threadIdx.x, w = tid >> 6, lane = tid & 63;
  const int cl = lane & 31, hf = lane >> 5;
  const int rg = w & 3, kh = w >> 2;
  const size_t bhoff = (size_t)bh * (LL * HDIM);

  __shared__ __align__(16) unsigned short smem[32768];  // 64 KB total
  unsigned short* Kbuf = smem;                // [2][64*64]
  unsigned short* Vbuf = smem + 8192;         // [2][64*64]
  unsigned short* myP  = smem + 16384 + w * 2048;  // [32 q][64], chunk-rotated

  // Q A-frags (loop-invariant): row = q0 + rg*32 + cl, k = 16ks + 8hf + j
  bf16x8 aq[4];
  {
    const unsigned short* qp = Qb + bhoff + (size_t)(q0 + rg * 32 + cl) * HDIM + hf * 8;
#pragma unroll
    for (int ks = 0; ks < 4; ++ks) aq[ks] = ld_frag(qp + ks * 16);
  }

  // staging: wave w stages K rows [8w,+8) and V d-rows [8w,+8): 1 async each per kt
  const int srow = lane >> 3;
  const int gcs = ((lane & 7) - srow) & 7;
  const unsigned short* kgp = Kb + bhoff + (size_t)(w * 8 + srow) * 64 + gcs * 8;
  const unsigned short* vgp = Vt + bhoff + (size_t)(w * 8 + srow) * 64 + gcs * 8;

  i32x4 onesi = {0x3F803F80, 0x3F803F80, 0x3F803F80, 0x3F803F80};
  bf16x8 vones = __builtin_bit_cast(bf16x8, onesi);

  f32x16 oacc0 = (f32x16)0.0f, oacc1 = (f32x16)0.0f, liacc = (f32x16)0.0f;

  // em_t[b][kt][kh][c=cl][q]; lane reads 4x b64 at q-offsets 8m (rows 8m+4hf+0..3)
  const unsigned short* ebase =
      Em + ((((size_t)b * 32) * 2 + kh) * 32 + cl) * LL + (q0 + rg * 32 + 4 * hf);

  // prologue: stage tile 0, load em(0)
  async_cp16(kgp, Kbuf + w * 512);
  async_cp16(vgp, Vbuf + w * 512);
  uint2 emv[4];
#pragma unroll
  for (int m = 0; m < 4; ++m)
    emv[m] = *reinterpret_cast<const uint2*>(ebase + m * 8);

#pragma unroll 2
  for (int kt = 0; kt < 32; ++kt) {
    const int buf = kt & 1;
    __syncthreads();  // drains own asyncs -> tile kt ready; prior reads of buf^1 done
    if (kt + 1 < 32) {
      const int nb = buf ^ 1;
      async_cp16(kgp + (size_t)(kt + 1) * 4096, Kbuf + nb * 4096 + w * 512);
      async_cp16(vgp + (size_t)(kt + 1) * 4096, Vbuf + nb * 4096 + w * 512);
    }
    const int ktn = (kt + 1 < 32) ? kt + 1 : 31;
    uint2 emn[4];
#pragma unroll
    for (int m = 0; m < 4; ++m)
      emn[m] = *reinterpret_cast<const uint2*>(ebase + (size_t)ktn * 131072 + m * 8);

    // S = Q @ K^T for this wave's 32-key half
    bf16x8 bkf[4];
#pragma unroll
    for (int ks = 0; ks < 4; ++ks) {
      int row = kh * 32 + cl;
      bkf[ks] = ld_frag(&Kbuf[buf * 4096 + row * 64 + ((2 * ks + hf + row) & 7) * 8]);
    }
    f32x16 sacc = (f32x16)0.0f;
#pragma unroll
    for (int ks = 0; ks < 4; ++ks)
      sacc = __builtin_amdgcn_mfma_f32_32x32x16_bf16(aq[ks], bkf[ks], sacc, 0, 0, 0);

    // softmax: p = exp2(s) * em; 16 b16 stores into chunk-rotated wave-private P
#pragma unroll
    for (int m = 0; m < 4; ++m) {
      unsigned int ex = emv[m].x, ey = emv[m].y;
      float ef[4];
      ef[0] = __builtin_bit_cast(float, ex << 16);
      ef[1] = __builtin_bit_cast(float, ex & 0xffff0000u);
      ef[2] = __builtin_bit_cast(float, ey << 16);
      ef[3] = __builtin_bit_cast(float, ey & 0xffff0000u);
#pragma unroll
      for (int j = 0; j < 4; ++j) {
        int r = 4 * m + j;
        float p = __builtin_amdgcn_exp2f(sacc[r]) * ef[j];
        int qh = j + 8 * m + 4 * hf;
        myP[qh * 64 + (((cl >> 3) + qh) & 7) * 8 + (cl & 7)] =
            (unsigned short)(__builtin_bit_cast(unsigned int, p) >> 16);
      }
    }
    asm volatile("" ::: "memory");  // P stores ordered before same-wave P frag reads

    // O += P @ V (k = 32-key half); li += P @ ones
    bf16x8 ap[2];
#pragma unroll
    for (int ks = 0; ks < 2; ++ks)
      ap[ks] = ld_frag(&myP[cl * 64 + ((2 * ks + hf + cl) & 7) * 8]);
    bf16x8 bvf[2][2];
#pragma unroll
    for (int t = 0; t < 2; ++t)
#pragma unroll
      for (int ks = 0; ks < 2; ++ks) {
        int row = t * 32 + cl;
        bvf[t][ks] = ld_frag(
            &Vbuf[buf * 4096 + row * 64 + ((4 * kh + 2 * ks + hf + row) & 7) * 8]);
      }
#pragma unroll
    for (int ks = 0; ks < 2; ++ks) {
      oacc0 = __builtin_amdgcn_mfma_f32_32x32x16_bf16(ap[ks], bvf[0][ks], oacc0, 0, 0, 0);
      oacc1 = __builtin_amdgcn_mfma_f32_32x32x16_bf16(ap[ks], bvf[1][ks], oacc1, 0, 0, 0);
      liacc = __builtin_amdgcn_mfma_f32_32x32x16_bf16(ap[ks], vones, liacc, 0, 0, 0);
    }
#pragma unroll
    for (int m = 0; m < 4; ++m) emv[m] = emn[m];
  }

  // epilogue: merge key-half partners (w and w^4) via LDS, normalize, write fp32
  __syncthreads();
  float* Om = reinterpret_cast<float*>(smem);  // rg region: 2080 floats (O 32x64 + li 32)
  if (kh == 1) {
#pragma unroll
    for (int r = 0; r < 16; ++r) {
      int R = (r & 3) + 8 * (r >> 2) + 4 * hf;
      Om[rg * 2080 + R * 64 + cl]      = oacc0[r];
      Om[rg * 2080 + R * 64 + 32 + cl] = oacc1[r];
      if (cl == 0) Om[rg * 2080 + 2048 + R] = liacc[r];
    }
  }
  __syncthreads();
  if (kh == 0) {
#pragma unroll
    for (int r = 0; r < 16; ++r) {
      int R = (r & 3) + 8 * (r >> 2) + 4 * hf;
      float lsum = liacc[r] + Om[rg * 2080 + 2048 + R];
      float inv = 1.0f / lsum;
      int q = q0 + rg * 32 + R;
      float* op = out + ((size_t)b * LL + q) * 1024 + h * 64 + cl;
      op[0]  = (oacc0[r] + Om[rg * 2080 + R * 64 + cl])      * inv;
      op[32] = (oacc1[r] + Om[rg * 2080 + R * 64 + 32 + cl]) * inv;
    }
  }
}

extern "C" void kernel_launch(void* const* d_in, const int* in_sizes, int n_in,
                              void* d_out, int out_size, void* d_ws, size_t ws_size,
                              hipStream_t stream) {
  const float* x    = (const float*)d_in[0];
  const float* mask = (const float*)d_in[1];
  const float* Wq   = (const float*)d_in[2];
  const float* bq   = (const float*)d_in[3];
  const float* Wk   = (const float*)d_in[4];
  const float* bk   = (const float*)d_in[5];
  const float* Wv   = (const float*)d_in[6];
  const float* bv   = (const float*)d_in[7];
  float* out = (float*)d_out;
  (void)in_sizes; (void)n_in; (void)out_size; (void)ws_size;

  char* ws = (char*)d_ws;
  // qkv @0 (24 MiB); xb @24 (8 MiB); Wt @32 (6 MiB);
  // em @24 (16.8 MiB) overlaps xb/Wt — dead after qkv_gemm; em_prep MUST launch after qkv_gemm.
  unsigned short* qkv = (unsigned short*)(ws);
  unsigned short* xb  = (unsigned short*)(ws + (24u << 20));
  unsigned short* Wt  = (unsigned short*)(ws + (32u << 20));
  unsigned short* em  = (unsigned short*)(ws + (24u << 20));

  prep_kernel<<<dim3(4864), dim3(256), 0, stream>>>(x, Wq, Wk, Wv, xb, Wt);
  qkv_gemm_kernel<<<dim3(8, 32, 3), dim3(256), 0, stream>>>(xb, Wt, bq, bk, bv, qkv);
  em_prep_kernel<<<dim3(2048), dim3(256), 0, stream>>>(mask, em);
  flash_kernel<<<dim3(16, 32), dim3(512), 0, stream>>>(qkv, qkv + 4194304, qkv + 8388608,
                                                       em, out);
}

// Round 8
// 216.988 us; speedup vs baseline: 1.1872x; 1.1872x over previous
//
#include <hip/hip_runtime.h>

// B=2, L=2048, DIM=1024, H=16, HD=64; scale folded into Q: 0.125*log2e; mask: -60*log2e
#define LL 2048
#define NHEADS 16
#define HDIM 64
#define QSCALE 0.18033688011112042f   // 0.125 * log2(e)
#define MASKC1 -86.56170245333780f    // -60 * log2(e)

typedef __attribute__((ext_vector_type(8))) __bf16 bf16x8;
typedef __attribute__((ext_vector_type(4))) float f32x4;

__device__ __forceinline__ unsigned short f2bf(float f) {
  unsigned int u = __builtin_bit_cast(unsigned int, f);
  u += 0x7fffu + ((u >> 16) & 1u);   // RNE
  return (unsigned short)(u >> 16);
}

__device__ __forceinline__ bf16x8 ld_frag(const unsigned short* p) {
  return *reinterpret_cast<const bf16x8*>(p);
}

// async global->LDS, 16B per lane; LDS dest = wave-uniform base + lane*16
__device__ __forceinline__ void async_cp16(const unsigned short* g, unsigned short* l) {
  __builtin_amdgcn_global_load_lds(
      (const __attribute__((address_space(1))) unsigned int*)(unsigned long long)(g),
      (__attribute__((address_space(3))) unsigned int*)(unsigned int)(unsigned long long)(l),
      16, 0, 0);
}

// ---------------- fused prep: x fp32->bf16 (blocks 0..4095) + W transpose (4096..4863) ----------
__global__ __launch_bounds__(256) void prep_kernel(
    const float* __restrict__ x, const float* __restrict__ Wq, const float* __restrict__ Wk,
    const float* __restrict__ Wv, unsigned short* __restrict__ xb,
    unsigned short* __restrict__ WtAll) {
  __shared__ float t[64][65];
  int blk = blockIdx.x;
  if (blk < 4096) {
    int i = (blk * 256 + threadIdx.x) * 4;
    float4 v = *reinterpret_cast<const float4*>(x + i);
    ushort4 o;
    o.x = f2bf(v.x); o.y = f2bf(v.y); o.z = f2bf(v.z); o.w = f2bf(v.w);
    *reinterpret_cast<ushort4*>(xb + i) = o;
  } else {
    int idx = blk - 4096;
    int z = idx >> 8; idx &= 255;
    const float* W = (z == 0) ? Wq : (z == 1) ? Wk : Wv;
    unsigned short* dst = WtAll + (size_t)z * 1024 * 1024;
    int n0 = (idx & 15) * 64, k0 = (idx >> 4) * 64;
    int tx = threadIdx.x & 63, ty = threadIdx.x >> 6;
#pragma unroll
    for (int p = 0; p < 16; ++p) {
      int kr = p * 4 + ty;
      t[kr][tx] = W[(size_t)(k0 + kr) * 1024 + n0 + tx];
    }
    __syncthreads();
#pragma unroll
    for (int p = 0; p < 16; ++p) {
      int nr = p * 4 + ty;
      dst[(size_t)(n0 + nr) * 1024 + k0 + tx] = f2bf(t[tx][nr]);
    }
  }
}

// ---------------- prep: em = bf16(exp2(mask*MASKC1)), key-permuted pos=4c+q ----------------
// grid (2, 4096): row = b*L+q; thread handles one (kb, c): reads cols kb*64+c+16q (q=0..3),
// writes ushort4 at kb*64+4c.
__global__ __launch_bounds__(256) void em_prep_kernel(const float* __restrict__ mask,
                                                      unsigned short* __restrict__ em) {
  int row = blockIdx.y;
  int t = blockIdx.x * 256 + threadIdx.x;
  int kb = t >> 4, c = t & 15;
  const float* src = mask + (size_t)row * LL + kb * 64 + c;
  ushort4 o;
  o.x = f2bf(__builtin_amdgcn_exp2f(src[0]  * MASKC1));
  o.y = f2bf(__builtin_amdgcn_exp2f(src[16] * MASKC1));
  o.z = f2bf(__builtin_amdgcn_exp2f(src[32] * MASKC1));
  o.w = f2bf(__builtin_amdgcn_exp2f(src[48] * MASKC1));
  *reinterpret_cast<ushort4*>(em + (size_t)row * LL + kb * 64 + 4 * c) = o;
}

// ---------------- QKV projection GEMM (async staging, swizzled rows) ----------------
// grid (8, 32, 3). z==0: Q bf16 [bh][l][d] * QSCALE; z==1: K [bh][l][d];
// z==2: V^T [bh][d][l], pos=4c+q permuted within each 64-block of l.
// Q/K epilogue now LDS-staged -> fully coalesced uint4 global stores.
__global__ __launch_bounds__(256) void qkv_gemm_kernel(
    const unsigned short* __restrict__ xb, const unsigned short* __restrict__ WtAll,
    const float* __restrict__ bq, const float* __restrict__ bk, const float* __restrict__ bv,
    unsigned short* __restrict__ qkv) {
  const int z = blockIdx.z;
  const unsigned short* Wt = WtAll + (size_t)z * 1024 * 1024;
  const float* bias = (z == 0) ? bq : (z == 1) ? bk : bv;
  unsigned short* outb = qkv + (size_t)z * 4194304;

  __shared__ __align__(16) unsigned short smem[16896];  // As 8192 | Bs 8192; epi: 128x132
  unsigned short* As = smem;
  unsigned short* Bs = smem + 8192;

  const int tid = threadIdx.x;
  const int w = tid >> 6, lane = tid & 63, g = lane >> 4, cc = lane & 15;
  const int wm = w >> 1, wn = w & 1;
  const int m0 = blockIdx.y * 128, n0 = blockIdx.x * 128;
  const int srow = lane >> 3;
  const int gc = ((lane & 7) - srow) & 7;     // swizzle: LDS slot s holds chunk (s - row)&7
  const unsigned short* ga = xb + (size_t)(m0 + w * 32 + srow) * 1024 + gc * 8;
  const unsigned short* gb = Wt + (size_t)(n0 + w * 32 + srow) * 1024 + gc * 8;
  unsigned short* la = As + w * 2048;
  unsigned short* lb = Bs + w * 2048;

  f32x4 acc[4][4];
#pragma unroll
  for (int i = 0; i < 4; ++i)
#pragma unroll
    for (int j = 0; j < 4; ++j) acc[i][j] = (f32x4)0.0f;

  for (int kk = 0; kk < 1024; kk += 64) {
    __syncthreads();
#pragma unroll
    for (int i = 0; i < 4; ++i) {
      async_cp16(ga + i * 8192 + kk, la + i * 512);
      async_cp16(gb + i * 8192 + kk, lb + i * 512);
    }
    __syncthreads();
    bf16x8 af[4][2], bfr[4][2];
#pragma unroll
    for (int mt = 0; mt < 4; ++mt)
#pragma unroll
      for (int ks = 0; ks < 2; ++ks)
        af[mt][ks] = ld_frag(&As[(wm * 64 + mt * 16 + cc) * 64 + ((4 * ks + g + cc) & 7) * 8]);
#pragma unroll
    for (int nt = 0; nt < 4; ++nt)
#pragma unroll
      for (int ks = 0; ks < 2; ++ks)
        bfr[nt][ks] = ld_frag(&Bs[(wn * 64 + nt * 16 + cc) * 64 + ((4 * ks + g + cc) & 7) * 8]);
#pragma unroll
    for (int mt = 0; mt < 4; ++mt)
#pragma unroll
      for (int nt = 0; nt < 4; ++nt)
#pragma unroll
        for (int ks = 0; ks < 2; ++ks)
          acc[mt][nt] = __builtin_amdgcn_mfma_f32_16x16x32_bf16(af[mt][ks], bfr[nt][ks],
                                                                acc[mt][nt], 0, 0, 0);
  }

  __syncthreads();  // all frag reads done before smem reuse by epilogues
  if (z != 2) {
    // stage C (bf16, bias+scale applied) at stride 132 (2-way-free b16 writes)
    const float sc = (z == 0) ? QSCALE : 1.0f;
#pragma unroll
    for (int nt = 0; nt < 4; ++nt) {
      int nl = wn * 64 + nt * 16 + cc;
      float bval = bias[n0 + nl];
#pragma unroll
      for (int mt = 0; mt < 4; ++mt)
#pragma unroll
        for (int r = 0; r < 4; ++r) {
          int ml = wm * 64 + mt * 16 + g * 4 + r;
          smem[ml * 132 + nl] = f2bf((acc[mt][nt][r] + bval) * sc);
        }
    }
    __syncthreads();
    // coalesced write: idx over 2048 uint4 chunks; region = head half of the n-tile
    const int bb = m0 >> 11, l0 = m0 & 2047, h0 = n0 >> 6;
#pragma unroll
    for (int i = 0; i < 8; ++i) {
      int idx = i * 256 + tid;
      int region = idx >> 10, within = idx & 1023;
      int lrow = within >> 3, col = (within & 7) * 8;
      unsigned short* dst =
          outb + (((size_t)(bb * NHEADS + h0 + region) * LL) + l0 + lrow) * HDIM + col;
      *reinterpret_cast<uint4*>(dst) =
          *reinterpret_cast<const uint4*>(&smem[lrow * 132 + region * 64 + col]);
    }
  } else {
    // V^T epilogue with key permutation pos = 4c + q: local = mt*16+g*4+r -> pos = 16g+4r+mt
#pragma unroll
    for (int nt = 0; nt < 4; ++nt) {
      int nr = wn * 64 + nt * 16 + cc;
      float bval = bias[n0 + nr];
#pragma unroll
      for (int mt = 0; mt < 4; ++mt)
#pragma unroll
        for (int r = 0; r < 4; ++r)
          smem[nr * 128 + wm * 64 + 16 * g + 4 * r + mt] = f2bf(acc[mt][nt][r] + bval);
    }
    __syncthreads();
    int row = tid >> 1, half = tid & 1;
    int n = n0 + row, hh = n >> 6, dd = n & 63;
    int bb = m0 >> 11, l0 = (m0 & 2047) + half * 64;
    unsigned short* dst = outb + ((size_t)(bb * NHEADS + hh) * HDIM + dd) * LL + l0;
#pragma unroll
    for (int i = 0; i < 8; ++i)
      *reinterpret_cast<uint4*>(dst + i * 8) =
          *reinterpret_cast<const uint4*>(&smem[row * 128 + half * 64 + i * 8]);
  }
}

// ---------------- flash attention (R4-verified: 68 µs) ----------------
// grid (32, 32): 64-row q-tiles. LDS = exactly 40KB -> 4 blocks/CU (16 waves/CU).
// Ping-pong K/V via global_load_lds; Ps unpadded with 16B-chunk rotation swizzle.
__global__ __launch_bounds__(256, 4) void flash_kernel(
    const unsigned short* __restrict__ Qb, const unsigned short* __restrict__ Kb,
    const unsigned short* __restrict__ Vt, const unsigned short* __restrict__ Em,
    float* __restrict__ out) {
  const int bh = blockIdx.y, b = bh >> 4, h = bh & 15;
  const int q0 = blockIdx.x * 64;
  const int tid = threadIdx.x, w = tid >> 6, lane = tid & 63, g = lane >> 4, cc = lane & 15;
  const size_t bhoff = (size_t)bh * LL * HDIM;

  __shared__ __align__(16) unsigned short Ps[64 * 64];     // P tile, swizzled chunks
  __shared__ __align__(16) unsigned short Ks[2][64 * 64];  // [key][d], swizzled chunks
  __shared__ __align__(16) unsigned short Vs[2][64 * 64];  // [d][pos], swizzled chunks

  // Q fragments straight from global (loop-invariant); wave w owns q rows [w*16, w*16+16)
  bf16x8 aq[2];
#pragma unroll
  for (int ks = 0; ks < 2; ++ks)
    aq[ks] = *reinterpret_cast<const bf16x8*>(
        Qb + bhoff + (size_t)(q0 + w * 16 + cc) * HDIM + ks * 32 + g * 8);

  // async staging: wave w stages K segs {w, w+4} and V segs {w, w+4}
  const int srow = lane >> 3;
  const int gcs = ((lane & 7) - srow) & 7;
  const unsigned short* kg0 = Kb + bhoff + (size_t)(w * 8 + srow) * HDIM + gcs * 8;
  const unsigned short* kg1 = Kb + bhoff + (size_t)(32 + w * 8 + srow) * HDIM + gcs * 8;
  const unsigned short* vg0 = Vt + bhoff + (size_t)(w * 8 + srow) * LL + gcs * 8;
  const unsigned short* vg1 = Vt + bhoff + (size_t)(32 + w * 8 + srow) * LL + gcs * 8;

  float li[4];
  f32x4 oacc[4];
#pragma unroll
  for (int r = 0; r < 4; ++r) li[r] = 0.0f;
#pragma unroll
  for (int nt = 0; nt < 4; ++nt) oacc[nt] = (f32x4)0.0f;

  const unsigned short* embase = Em + ((size_t)b * LL + q0 + w * 16) * LL + 4 * cc;

  // stage tile 0 into buf 0
  async_cp16(kg0, Ks[0] + w * 512);
  async_cp16(kg1, Ks[0] + (w + 4) * 512);
  async_cp16(vg0, Vs[0] + w * 512);
  async_cp16(vg1, Vs[0] + (w + 4) * 512);

#pragma unroll 2
  for (int kt = 0; kt < 32; ++kt) {
    const int buf = kt & 1;
    __syncthreads();  // drains own asyncs -> tile kt ready; prior reads of buf^1 done
    if (kt + 1 < 32) {
      const int nb = buf ^ 1;
      async_cp16(kg0 + (size_t)(kt + 1) * 64 * HDIM, Ks[nb] + w * 512);
      async_cp16(kg1 + (size_t)(kt + 1) * 64 * HDIM, Ks[nb] + (w + 4) * 512);
      async_cp16(vg0 + (kt + 1) * 64, Vs[nb] + w * 512);
      async_cp16(vg1 + (kt + 1) * 64, Vs[nb] + (w + 4) * 512);
    }
    uint2 emv[4];
#pragma unroll
    for (int r = 0; r < 4; ++r)
      emv[r] = *reinterpret_cast<const uint2*>(embase + (size_t)(g * 4 + r) * LL + kt * 64);

    // S = Q @ K^T
    bf16x8 bk_[4][2];
#pragma unroll
    for (int nt = 0; nt < 4; ++nt)
#pragma unroll
      for (int ks = 0; ks < 2; ++ks)
        bk_[nt][ks] = ld_frag(&Ks[buf][(nt * 16 + cc) * 64 + ((4 * ks + g + cc) & 7) * 8]);
    f32x4 sacc[4];
#pragma unroll
    for (int nt = 0; nt < 4; ++nt) sacc[nt] = (f32x4)0.0f;
#pragma unroll
    for (int nt = 0; nt < 4; ++nt)
#pragma unroll
      for (int ks = 0; ks < 2; ++ks)
        sacc[nt] = __builtin_amdgcn_mfma_f32_16x16x32_bf16(aq[ks], bk_[nt][ks], sacc[nt], 0, 0, 0);

    // p = exp2(s) * em; pack 4 bf16 -> one b64 store at swizzled pos
#pragma unroll
    for (int r = 0; r < 4; ++r) {
      unsigned int ex = emv[r].x, ey = emv[r].y;
      float e0 = __builtin_bit_cast(float, ex << 16);
      float e1 = __builtin_bit_cast(float, ex & 0xffff0000u);
      float e2 = __builtin_bit_cast(float, ey << 16);
      float e3 = __builtin_bit_cast(float, ey & 0xffff0000u);
      float p0 = __builtin_amdgcn_exp2f(sacc[0][r]) * e0;
      float p1 = __builtin_amdgcn_exp2f(sacc[1][r]) * e1;
      float p2 = __builtin_amdgcn_exp2f(sacc[2][r]) * e2;
      float p3 = __builtin_amdgcn_exp2f(sacc[3][r]) * e3;
      unsigned int u01 = __builtin_amdgcn_perm(__builtin_bit_cast(unsigned int, p1),
                                               __builtin_bit_cast(unsigned int, p0),
                                               0x07060302u);
      unsigned int u23 = __builtin_amdgcn_perm(__builtin_bit_cast(unsigned int, p3),
                                               __builtin_bit_cast(unsigned int, p2),
                                               0x07060302u);
      li[r] += __builtin_bit_cast(float, u01 << 16) +
               __builtin_bit_cast(float, u01 & 0xffff0000u) +
               __builtin_bit_cast(float, u23 << 16) +
               __builtin_bit_cast(float, u23 & 0xffff0000u);
      uint2 pk; pk.x = u01; pk.y = u23;
      int prow = w * 16 + g * 4 + r;
      int poff = prow * 64 + ((((cc >> 1) + prow) & 7) << 3) + ((cc & 1) << 2);
      *reinterpret_cast<uint2*>(&Ps[poff]) = pk;
    }
    asm volatile("" ::: "memory");  // P stores before same-wave P frag reads

    // O += P @ V  (k-dim = pos, matches Vs column order)
    bf16x8 ap[2], bv[4][2];
    {
      int arow = w * 16 + cc;
#pragma unroll
      for (int ks = 0; ks < 2; ++ks)
        ap[ks] = ld_frag(&Ps[arow * 64 + (((ks * 4 + g + arow) & 7) << 3)]);
    }
#pragma unroll
    for (int nt = 0; nt < 4; ++nt)
#pragma unroll
      for (int ks = 0; ks < 2; ++ks)
        bv[nt][ks] = ld_frag(&Vs[buf][(nt * 16 + cc) * 64 + ((4 * ks + g + cc) & 7) * 8]);
#pragma unroll
    for (int nt = 0; nt < 4; ++nt)
#pragma unroll
      for (int ks = 0; ks < 2; ++ks)
        oacc[nt] = __builtin_amdgcn_mfma_f32_16x16x32_bf16(ap[ks], bv[nt][ks], oacc[nt], 0, 0, 0);
  }

  // epilogue: reduce li over cc-lanes, normalize, write [B, L, H*HD] fp32
#pragma unroll
  for (int r = 0; r < 4; ++r) {
    float s = li[r];
    s += __shfl_xor(s, 1);
    s += __shfl_xor(s, 2);
    s += __shfl_xor(s, 4);
    s += __shfl_xor(s, 8);
    float inv = 1.0f / s;
    int qrow = q0 + w * 16 + g * 4 + r;
#pragma unroll
    for (int nt = 0; nt < 4; ++nt)
      out[((size_t)b * LL + qrow) * 1024 + h * 64 + nt * 16 + cc] = oacc[nt][r] * inv;
  }
}

extern "C" void kernel_launch(void* const* d_in, const int* in_sizes, int n_in,
                              void* d_out, int out_size, void* d_ws, size_t ws_size,
                              hipStream_t stream) {
  const float* x    = (const float*)d_in[0];
  const float* mask = (const float*)d_in[1];
  const float* Wq   = (const float*)d_in[2];
  const float* bq   = (const float*)d_in[3];
  const float* Wk   = (const float*)d_in[4];
  const float* bk   = (const float*)d_in[5];
  const float* Wv   = (const float*)d_in[6];
  const float* bv   = (const float*)d_in[7];
  float* out = (float*)d_out;
  (void)in_sizes; (void)n_in; (void)out_size; (void)ws_size;

  char* ws = (char*)d_ws;
  // qkv @0 (24 MiB); xb @24 (8 MiB); Wt @32 (6 MiB);
  // em @24 (16 MiB) overlaps xb/Wt — dead after qkv_gemm; em_prep MUST launch after qkv_gemm.
  unsigned short* qkv = (unsigned short*)(ws);
  unsigned short* xb  = (unsigned short*)(ws + (24u << 20));
  unsigned short* Wt  = (unsigned short*)(ws + (32u << 20));
  unsigned short* em  = (unsigned short*)(ws + (24u << 20));

  prep_kernel<<<dim3(4864), dim3(256), 0, stream>>>(x, Wq, Wk, Wv, xb, Wt);
  qkv_gemm_kernel<<<dim3(8, 32, 3), dim3(256), 0, stream>>>(xb, Wt, bq, bk, bv, qkv);
  em_prep_kernel<<<dim3(2, 4096), dim3(256), 0, stream>>>(mask, em);
  flash_kernel<<<dim3(32, 32), dim3(256), 0, stream>>>(qkv, qkv + 4194304, qkv + 8388608,
                                                       em, out);
}